// Round 20
// baseline (97.366 us; speedup 1.0000x reference)
//
#include <hip/hip_runtime.h>
#include <hip/hip_bf16.h>

#define NHALF 4096
#define TWO_N 8192
#define DDIM 256
#define INV_T 10.0f
// 10 * log2(e): exp(10*s) = exp2(s * SCALE) where s is the raw cosine dot
#define SCALE 14.426950408889634f
// znB fragment-packed layout: byte(kb, row, lk) = kb*KBSTRIDE + row*64 + lk*16
// holding zn[row][kb*32 + lk*8 .. +7] as 16B of bf16.
#define KBSTRIDE ((size_t)TWO_N * 64)

typedef __bf16 v8bf __attribute__((ext_vector_type(8)));
typedef float f32x4 __attribute__((ext_vector_type(4)));

#if __has_builtin(__builtin_amdgcn_exp2f)
#define EXP2F(x) __builtin_amdgcn_exp2f(x)
#else
#define EXP2F(x) exp2f(x)
#endif

static __device__ __forceinline__ unsigned int f2bf(float x) {
    __hip_bfloat16 h = __float2bfloat16(x);
    return (unsigned int)*(unsigned short*)&h;
}

// ---- kernel 1: normalize rows -> fragment-packed bf16 znB; zero rowacc/out --
__global__ __launch_bounds__(256) void ntx_norm_kernel(
    const float* __restrict__ zi, const float* __restrict__ zj,
    char* __restrict__ znB, float* __restrict__ rowacc,
    float* __restrict__ out) {
    const int w = threadIdx.x >> 6;
    const int lane = threadIdx.x & 63;
    const int r = blockIdx.x * 4 + w;
    const float* src = (r < NHALF) ? (zi + (size_t)r * DDIM)
                                   : (zj + (size_t)(r - NHALF) * DDIM);
    float4 v = ((const float4*)src)[lane];
    float ss = v.x * v.x + v.y * v.y + v.z * v.z + v.w * v.w;
#pragma unroll
    for (int m = 1; m < 64; m <<= 1) ss += __shfl_xor(ss, m);
    float rinv = 1.0f / fmaxf(sqrtf(ss), 1e-8f);
    uint2 pk;
    pk.x = f2bf(v.x * rinv) | (f2bf(v.y * rinv) << 16);
    pk.y = f2bf(v.z * rinv) | (f2bf(v.w * rinv) << 16);
    char* dst = znB + (size_t)(lane >> 3) * KBSTRIDE + (size_t)r * 64 +
                ((lane >> 1) & 3) * 16 + (lane & 1) * 8;
    *(uint2*)dst = pk;
    if (blockIdx.x < 32) rowacc[blockIdx.x * 256 + threadIdx.x] = 0.0f;
    if (blockIdx.x == 0 && threadIdx.x == 0) out[0] = 0.0f;
}

// ---- kernel 2: symmetric Gram + exp sums — 32-row strips, AGPR-A, 4 w/SIMD --
// Register-file split designed exactly for gfx950's unified RF:
//   af[2][8] = 64 AGPRs, pinned "+a" IMMEDIATELY per fragment (R19 failure:
//   pinning after all 32 loads left a 128-VGPR entry spike -> spill);
//   arch VGPRs = bf[8] 32 + acc[2] 8 + rowsum 8 + misc ~14 = ~62.
// __launch_bounds__(256,4) caps arch at 64 (R17 evidence) -> 64a+64v = 128
// unified = 4 waves/SIMD, no spill (R17's same bound was fatal at demand 122;
// now demand fits). 16 waves/CU x 8 outstanding B-loads hide ~200cyc L2 lat
// (R12-R19: 2 waves/SIMD -> ~30us of aligned-stall exposure).
// Task map (verified absmax=0 in R17/R18): 32-row x 64-col strips; 16512
// strips = 4128 tasks x 4; 1032 blocks x 4 waves (~4.03/CU, ~1.01 rounds).
// Tasks 0..31: the 128 positive (d=64) strips, af reloaded per strip, spos
// written for row and row+4096. Tasks 32..4127: t=task-32, rt128=t>>5,
// half=(t>>4)&1, g=t&15, d=4g..4g+3, ct=(rt128-d) mod 128. d==0: self ->
// mask local diag, skip col-sums; else col-sums (mirror) -> rowacc[C0 cols].
__global__ __launch_bounds__(256, 4) void ntx_gram_kernel(
    const char* __restrict__ znB,
    float* __restrict__ rowacc,    // [TWO_N] atomic accumulation
    float* __restrict__ spos) {    // [TWO_N]
    const int tid = threadIdx.x;
    const int w = tid >> 6, lane = tid & 63;
    const int task = blockIdx.x * 4 + w;
    const int lrow = lane & 15, lk = lane >> 4;
    const int diagj = lrow - lk * 4;   // od(j) <=> diagj == j

    f32x4 af[2][8], bf[8];
    float rowsum[2][4];
    int R0, halfv;

#define LOAD_AF()                                                             \
    do {                                                                      \
        _Pragma("unroll")                                                     \
        for (int rf = 0; rf < 2; ++rf) {                                      \
            const char* ab =                                                  \
                znB + (size_t)(R0 + rf * 16 + lrow) * 64 + lk * 16;           \
            _Pragma("unroll")                                                 \
            for (int kb = 0; kb < 8; ++kb) {                                  \
                af[rf][kb] = *(const f32x4*)(ab + kb * KBSTRIDE);             \
                asm volatile("" : "+a"(af[rf][kb])); /* pin NOW: no spike */  \
            }                                                                 \
        }                                                                     \
    } while (0)

#define ZERO_RS()                                                             \
    do {                                                                      \
        _Pragma("unroll")                                                     \
        for (int rf = 0; rf < 2; ++rf)                                        \
            _Pragma("unroll")                                                 \
            for (int j = 0; j < 4; ++j) rowsum[rf][j] = 0.0f;                 \
    } while (0)

// one cf-step: 16 cols, all 8 B-loads issued back-to-back, then 16 MFMA
#define CFSTEP(cf, C0, SELF, POSB)                                            \
    do {                                                                      \
        _Pragma("unroll")                                                     \
        for (int kb = 0; kb < 8; ++kb)                                        \
            bf[kb] = *(const f32x4*)(zcb + (cf) * 1024 + kb * KBSTRIDE);      \
        f32x4 acc[2];                                                         \
        acc[0] = (f32x4){0.f, 0.f, 0.f, 0.f};                                 \
        acc[1] = (f32x4){0.f, 0.f, 0.f, 0.f};                                 \
        _Pragma("unroll")                                                     \
        for (int kb = 0; kb < 8; ++kb) {                                      \
            acc[0] = __builtin_amdgcn_mfma_f32_16x16x32_bf16(                 \
                __builtin_bit_cast(v8bf, af[0][kb]),                          \
                __builtin_bit_cast(v8bf, bf[kb]), acc[0], 0, 0, 0);           \
            acc[1] = __builtin_amdgcn_mfma_f32_16x16x32_bf16(                 \
                __builtin_bit_cast(v8bf, af[1][kb]),                          \
                __builtin_bit_cast(v8bf, bf[kb]), acc[1], 0, 0, 0);           \
        }                                                                     \
        float ce = 0.0f;                                                      \
        _Pragma("unroll")                                                     \
        for (int rf = 0; rf < 2; ++rf) {                                      \
            const bool dfrag = ((cf) == halfv * 2 + rf);                      \
            _Pragma("unroll")                                                 \
            for (int j = 0; j < 4; ++j) {                                     \
                const float sv = acc[rf][j];                                  \
                const bool od = dfrag && (diagj == j);                        \
                if ((POSB) && od) {                                           \
                    const int u = R0 + rf * 16 + lk * 4 + j;                  \
                    spos[u] = sv * INV_T;                                     \
                    spos[u + NHALF] = sv * INV_T;                             \
                }                                                             \
                float e = EXP2F(sv * SCALE);                                  \
                e = ((SELF) && od) ? 0.0f : e;                                \
                rowsum[rf][j] += e;                                           \
                ce += e;                                                      \
            }                                                                 \
        }                                                                     \
        if (!(SELF)) {                                                        \
            ce += __shfl_xor(ce, 16);                                         \
            ce += __shfl_xor(ce, 32);                                         \
            if (lane < 16)                                                    \
                atomicAdd(&rowacc[(C0) + (cf) * 16 + lrow], ce);              \
        }                                                                     \
    } while (0)

#define DO_TILE(C0, SELF, POSB)                                               \
    do {                                                                      \
        const char* zcb = znB + (size_t)((C0) + lrow) * 64 + lk * 16;         \
        CFSTEP(0, C0, SELF, POSB);                                            \
        CFSTEP(1, C0, SELF, POSB);                                            \
        CFSTEP(2, C0, SELF, POSB);                                            \
        CFSTEP(3, C0, SELF, POSB);                                            \
    } while (0)

#define FLUSH_RS()                                                            \
    do {                                                                      \
        _Pragma("unroll")                                                     \
        for (int rf = 0; rf < 2; ++rf) {                                      \
            _Pragma("unroll")                                                 \
            for (int j = 0; j < 4; ++j) {                                     \
                float v = rowsum[rf][j];                                      \
                v += __shfl_xor(v, 1);                                        \
                v += __shfl_xor(v, 2);                                        \
                v += __shfl_xor(v, 4);                                        \
                v += __shfl_xor(v, 8);                                        \
                if (lrow == 0)                                                \
                    atomicAdd(&rowacc[R0 + rf * 16 + lk * 4 + j], v);         \
            }                                                                 \
        }                                                                     \
    } while (0)

    if (task < 32) {
        // positive strips: p = task*4+s in [0,128); rows p*32..+31,
        // cols = (p>>1)*64 + 4096 (d=64, no wrap).
#pragma unroll 1
        for (int s = 0; s < 4; ++s) {
            const int p = task * 4 + s;
            R0 = p * 32;
            halfv = p & 1;
            const int C0 = (p >> 1) * 64 + NHALF;
            LOAD_AF();
            ZERO_RS();
            DO_TILE(C0, false, true);
            FLUSH_RS();
        }
    } else {
        const int t = task - 32;
        const int rt128 = t >> 5, g = t & 15;
        halfv = (t >> 4) & 1;
        R0 = rt128 * 64 + halfv * 32;
        LOAD_AF();
        ZERO_RS();
#pragma unroll 1
        for (int s = 0; s < 4; ++s) {
            const int d = g * 4 + s;
            const int ct = ((rt128 - d) + 128) & 127;
            const int C0 = ct * 64;
            if (d == 0) {
                DO_TILE(C0, true, false);
            } else {
                DO_TILE(C0, false, false);
            }
        }
        FLUSH_RS();
    }
#undef LOAD_AF
#undef ZERO_RS
#undef CFSTEP
#undef DO_TILE
#undef FLUSH_RS
}

// ---------------- kernel 3: finalize ----------------
__global__ __launch_bounds__(256) void ntx_final_kernel(
    const float* __restrict__ rowacc, const float* __restrict__ spos,
    float* __restrict__ out) {
    const int tid = threadIdx.x;
    const int r = blockIdx.x * 256 + tid;
    float nll = logf(rowacc[r]) - spos[r];
    __shared__ float red[256];
    red[tid] = nll;
    __syncthreads();
    for (int s = 128; s > 0; s >>= 1) {
        if (tid < s) red[tid] += red[tid + s];
        __syncthreads();
    }
    if (tid == 0) atomicAdd(out, red[0] * (1.0f / (float)TWO_N));
}

extern "C" void kernel_launch(void* const* d_in, const int* in_sizes, int n_in,
                              void* d_out, int out_size, void* d_ws, size_t ws_size,
                              hipStream_t stream) {
    const float* zi = (const float*)d_in[0];
    const float* zj = (const float*)d_in[1];
    char* ws = (char*)d_ws;
    char* znB = ws;                                                    // 4 MB
    size_t off = (size_t)TWO_N * DDIM * 2;
    float* spos = (float*)(ws + off);                                  // 32 KB
    off += (size_t)TWO_N * 4;
    float* rowacc = (float*)(ws + off);                                // 32 KB
    float* out = (float*)d_out;

    ntx_norm_kernel<<<TWO_N / 4, 256, 0, stream>>>(zi, zj, znB, rowacc, out);
    ntx_gram_kernel<<<1032, 256, 0, stream>>>(znB, rowacc, spos);
    ntx_final_kernel<<<TWO_N / 256, 256, 0, stream>>>(rowacc, spos, out);
}

// Round 21
// 46.769 us; speedup vs baseline: 2.0818x; 2.0818x over previous
//
#include <hip/hip_runtime.h>
#include <hip/hip_bf16.h>

#define NHALF 4096
#define TWO_N 8192
#define DDIM 256
#define INV_T 10.0f
// 10 * log2(e): exp(10*s) = exp2(s * SCALE) where s is the raw cosine dot
#define SCALE 14.426950408889634f
// znB fragment-packed layout: byte(kb, row, lk) = kb*KBSTRIDE + row*64 + lk*16
// holding zn[row][kb*32 + lk*8 .. +7] as 16B of bf16.
#define KBSTRIDE ((size_t)TWO_N * 64)

typedef __bf16 v8bf __attribute__((ext_vector_type(8)));
typedef float f32x4 __attribute__((ext_vector_type(4)));

#if __has_builtin(__builtin_amdgcn_exp2f)
#define EXP2F(x) __builtin_amdgcn_exp2f(x)
#else
#define EXP2F(x) exp2f(x)
#endif

static __device__ __forceinline__ unsigned int f2bf(float x) {
    __hip_bfloat16 h = __float2bfloat16(x);
    return (unsigned int)*(unsigned short*)&h;
}

// ---- kernel 1: normalize rows -> fragment-packed bf16 znB; zero colpart/out -
// 2048 blocks x 256 thr; thread (b,t) also zeroes colpart[b*256+t]
// (2048*256 = 524288 = 64*8192 exactly).
__global__ __launch_bounds__(256) void ntx_norm_kernel(
    const float* __restrict__ zi, const float* __restrict__ zj,
    char* __restrict__ znB, float* __restrict__ colpart,
    float* __restrict__ out) {
    const int w = threadIdx.x >> 6;
    const int lane = threadIdx.x & 63;
    const int r = blockIdx.x * 4 + w;
    const float* src = (r < NHALF) ? (zi + (size_t)r * DDIM)
                                   : (zj + (size_t)(r - NHALF) * DDIM);
    float4 v = ((const float4*)src)[lane];
    float ss = v.x * v.x + v.y * v.y + v.z * v.z + v.w * v.w;
#pragma unroll
    for (int m = 1; m < 64; m <<= 1) ss += __shfl_xor(ss, m);
    float rinv = 1.0f / fmaxf(sqrtf(ss), 1e-8f);
    uint2 pk;
    pk.x = f2bf(v.x * rinv) | (f2bf(v.y * rinv) << 16);
    pk.y = f2bf(v.z * rinv) | (f2bf(v.w * rinv) << 16);
    char* dst = znB + (size_t)(lane >> 3) * KBSTRIDE + (size_t)r * 64 +
                ((lane >> 1) & 3) * 16 + (lane & 1) * 8;
    *(uint2*)dst = pk;
    colpart[(size_t)blockIdx.x * 256 + threadIdx.x] = 0.0f;
    if (blockIdx.x == 0 && threadIdx.x == 0) out[0] = 0.0f;
}

// ---- kernel 2: symmetric Gram + exp sums — BARRIER-FREE, LDS-FREE, -------
// ----------------------------- ATOMIC-FREE hot loop -----------------------
// EXACT Round-12 kernel (best measured: 44.7 us total, gram ~37 us) with the
// per-cf-step global atomicAdds replaced by plain stores. Theory: vmcnt
// completion is tracked in ISSUE ORDER, so the ~600-1000cyc L2 atomic RMW in
// each cf-step forced every later s_waitcnt vmcnt(N) (for the next B batch)
// to drain past it -> one atomic round-trip serialized into every cf-step
// (~4.3k stall cyc/step measured vs ~900 issue cyc). Stores ack fast and
// need no drain before the next loads' waitcnt.
//   col-sums -> colpart[d-1][8192] (d=1..63) / colpart[63][] (d=64);
//     unique writer per (d,col); cols 0..4095 of slot 63 stay zero (init).
//   row-sums -> rowpart[g][8192]; unique writer per (g,row).
// Finalize sums the 80 partials. Map unchanged from R12: 128 row-tiles;
// task=(rt,g): d=4g..4g+3, ct=(rt-d) mod 128; g==15&rt<64 adds d=64 tile
// (positive pairs, spos both halves). d==0: self -> mask diag, no col-sums.
__global__ __launch_bounds__(256, 2) void ntx_gram_kernel(
    const char* __restrict__ znB,
    float* __restrict__ rowpart,   // [16][TWO_N]
    float* __restrict__ colpart,   // [64][TWO_N]
    float* __restrict__ spos) {    // [TWO_N]
    const int tid = threadIdx.x;
    const int w = tid >> 6, lane = tid & 63;
    const int task = blockIdx.x * 4 + w;
    const int rt = task >> 4, g = task & 15;
    const int rbase = rt * 64;
    const int lrow = lane & 15, lk = lane >> 4;
    const int nt = (g == 15 && rt < 64) ? 5 : 4;

    // A fragments for the full K=256: af[rf][kb]
    f32x4 af[4][8];
#pragma unroll
    for (int rf = 0; rf < 4; ++rf) {
        const char* ab =
            znB + (size_t)(rbase + rf * 16 + lrow) * 64 + lk * 16;
#pragma unroll
        for (int kb = 0; kb < 8; ++kb)
            af[rf][kb] = *(const f32x4*)(ab + kb * KBSTRIDE);
    }
#pragma unroll
    for (int rf = 0; rf < 4; ++rf)
#pragma unroll
        for (int kb = 0; kb < 8; ++kb)
            asm volatile("" : "+v"(af[rf][kb]));  // pin: no remat/sink

    bool odg[4];
#pragma unroll
    for (int j = 0; j < 4; ++j) odg[j] = (lrow == lk * 4 + j);

    float rowsum[4][4];
#pragma unroll
    for (int rf = 0; rf < 4; ++rf)
#pragma unroll
        for (int j = 0; j < 4; ++j) rowsum[rf][j] = 0.0f;

#define LOADB(bf, cf)                                                         \
    do {                                                                      \
        _Pragma("unroll")                                                     \
        for (int kb = 0; kb < 8; ++kb)                                        \
            bf[kb] = *(const f32x4*)(zcb + (cf) * 1024 + kb * KBSTRIDE);      \
    } while (0)

#define COMPUTE_EPI(bf, cf)                                                   \
    do {                                                                      \
        f32x4 acc[4];                                                         \
        _Pragma("unroll")                                                     \
        for (int rf = 0; rf < 4; ++rf) acc[rf] = (f32x4){0.f, 0.f, 0.f, 0.f}; \
        _Pragma("unroll")                                                     \
        for (int kb = 0; kb < 8; ++kb) {                                      \
            _Pragma("unroll")                                                 \
            for (int rf = 0; rf < 4; ++rf)                                    \
                acc[rf] = __builtin_amdgcn_mfma_f32_16x16x32_bf16(            \
                    __builtin_bit_cast(v8bf, af[rf][kb]),                     \
                    __builtin_bit_cast(v8bf, bf[kb]), acc[rf], 0, 0, 0);      \
        }                                                                     \
        float ce = 0.0f;                                                      \
        _Pragma("unroll")                                                     \
        for (int rf = 0; rf < 4; ++rf) {                                      \
            const bool dfrag = (rf == (cf));                                  \
            _Pragma("unroll")                                                 \
            for (int j = 0; j < 4; ++j) {                                     \
                const float sv = acc[rf][j];                                  \
                const bool od = dfrag && odg[j];                              \
                if (posb && od) {                                             \
                    const int u = rf * 16 + lk * 4 + j;                       \
                    spos[rbase + u] = sv * INV_T;                             \
                    spos[cb + u] = sv * INV_T;                                \
                }                                                             \
                float e = EXP2F(sv * SCALE);                                  \
                e = (self && od) ? 0.0f : e;                                  \
                rowsum[rf][j] += e;                                           \
                ce += e;                                                      \
            }                                                                 \
        }                                                                     \
        if (!self) {                                                          \
            ce += __shfl_xor(ce, 16);                                         \
            ce += __shfl_xor(ce, 32);                                         \
            if (lane < 16)                                                    \
                cpd[cb + (cf) * 16 + lrow] = ce;   /* plain store, no RMW */  \
        }                                                                     \
    } while (0)

#pragma unroll 1
    for (int s = 0; s < nt; ++s) {
        const int d = (s < 4) ? (g * 4 + s) : 64;
        const int ct = (rt - d + 128) & 127;
        const int cb = ct * 64;
        const bool self = (d == 0);
        const bool posb = (d == 64);
        float* cpd = colpart + (size_t)(d - 1) * TWO_N;  // d>=1 when used
        const char* zcb = znB + (size_t)(cb + lrow) * 64 + lk * 16;
        f32x4 bfA[8], bfB[8];
        LOADB(bfA, 0);
        LOADB(bfB, 1);
        COMPUTE_EPI(bfA, 0);
        LOADB(bfA, 2);
        COMPUTE_EPI(bfB, 1);
        LOADB(bfB, 3);
        COMPUTE_EPI(bfA, 2);
        COMPUTE_EPI(bfB, 3);
    }
#undef LOADB
#undef COMPUTE_EPI

    // flush row-sums: reduce over the 16 col-lanes, plain store to rowpart[g]
#pragma unroll
    for (int rf = 0; rf < 4; ++rf) {
#pragma unroll
        for (int j = 0; j < 4; ++j) {
            float v = rowsum[rf][j];
            v += __shfl_xor(v, 1);
            v += __shfl_xor(v, 2);
            v += __shfl_xor(v, 4);
            v += __shfl_xor(v, 8);
            if (lrow == 0)
                rowpart[(size_t)g * TWO_N + rbase + rf * 16 + lk * 4 + j] = v;
        }
    }
}

// ---------------- kernel 3: finalize (sum 16 row + 64 col partials) ---------
__global__ __launch_bounds__(256) void ntx_final_kernel(
    const float* __restrict__ rowpart, const float* __restrict__ colpart,
    const float* __restrict__ spos, float* __restrict__ out) {
    const int tid = threadIdx.x;
    const int r = blockIdx.x * 256 + tid;
    float se = 0.0f;
#pragma unroll
    for (int gq = 0; gq < 16; ++gq) se += rowpart[(size_t)gq * TWO_N + r];
#pragma unroll 8
    for (int k = 0; k < 64; ++k) se += colpart[(size_t)k * TWO_N + r];
    float nll = logf(se) - spos[r];
    __shared__ float red[256];
    red[tid] = nll;
    __syncthreads();
    for (int s = 128; s > 0; s >>= 1) {
        if (tid < s) red[tid] += red[tid + s];
        __syncthreads();
    }
    if (tid == 0) atomicAdd(out, red[0] * (1.0f / (float)TWO_N));
}

extern "C" void kernel_launch(void* const* d_in, const int* in_sizes, int n_in,
                              void* d_out, int out_size, void* d_ws, size_t ws_size,
                              hipStream_t stream) {
    const float* zi = (const float*)d_in[0];
    const float* zj = (const float*)d_in[1];
    char* ws = (char*)d_ws;
    char* znB = ws;                                                    // 4 MB
    size_t off = (size_t)TWO_N * DDIM * 2;
    float* spos = (float*)(ws + off);                                  // 32 KB
    off += (size_t)TWO_N * 4;
    float* rowpart = (float*)(ws + off);                               // 512 KB
    off += (size_t)16 * TWO_N * 4;
    float* colpart = (float*)(ws + off);                               // 2 MB
    float* out = (float*)d_out;

    ntx_norm_kernel<<<TWO_N / 4, 256, 0, stream>>>(zi, zj, znB, colpart, out);
    ntx_gram_kernel<<<512, 256, 0, stream>>>(znB, rowpart, colpart, spos);
    ntx_final_kernel<<<TWO_N / 256, 256, 0, stream>>>(rowpart, colpart, spos, out);
}